// Round 9
// baseline (329.558 us; speedup 1.0000x reference)
//
#include <hip/hip_runtime.h>

typedef unsigned short u16;
typedef short v8s __attribute__((ext_vector_type(8)));
typedef float v4f __attribute__((ext_vector_type(4)));
typedef u16  v4u __attribute__((ext_vector_type(4)));

__device__ __forceinline__ float bf2f(u16 h){ return __uint_as_float(((unsigned)h)<<16); }
__device__ __forceinline__ u16 f2bf(float f){
  unsigned u = __float_as_uint(f);
  u += 0x7FFFu + ((u>>16)&1u);
  return (u16)(u>>16);
}
__device__ __forceinline__ float siluf(float x){ return x/(1.f+__expf(-x)); }
__device__ __forceinline__ float softplusf(float x){
  return (x>15.f) ? x : __logf(1.f+__expf(x));
}
// async global->LDS, 16B/lane; HW dest = wave-uniform base + lane*16
__device__ __forceinline__ void gl16(const u16* g, u16* l){
  __builtin_amdgcn_global_load_lds(
    (const __attribute__((address_space(1))) void*)g,
    (__attribute__((address_space(3))) void*)l, 16, 0, 0);
}

// ---------------------------------------------------------------------------
// Setup mega-kernel (3 jobs by block range):
//  [0,9984)      f32->bf16 weight cvt; ln_g folded into W_inproj (W'=g*W)
//  [9984,13056)  prep sg[e]=sum_k g*W, cb[e]=sum_k beta*W
//  [13056,13184) input MLP as MFMA GEMM -> h,hb + layer0 LN stats (atomics;
//                stats buffer pre-zeroed by hipMemsetAsync)
// ---------------------------------------------------------------------------
struct SetupP {
  const float *x,*w_in,*b_in,*ln_g,*ln_b,*W_inproj,*W_xproj,*W_dt,*W_outproj;
  u16 *wIn,*wX,*wDt,*wOut;
  float *sg,*cb,*h,*st0;
  u16 *hb;
};

__global__ __launch_bounds__(256) void setup_kernel(SetupP sp)
{
  __shared__ u16 As[64*72], Bs[64*72];
  const int blk = blockIdx.x, t = threadIdx.x;
  if(blk < 9984){                        // ---- cvt ----
    const int c0=6291456, c1=c0+589824, c2=c1+196608;
    int i4 = (blk*256 + t)*4;
    float4 v; u16* dst;
    if(i4 < c0){
      v = *(const float4*)(sp.W_inproj + i4);
      int k = i4 & 511, l = (i4>>9)/3072;
      const float* gg = sp.ln_g + l*512 + k;
      v.x*=gg[0]; v.y*=gg[1]; v.z*=gg[2]; v.w*=gg[3];
      dst = sp.wIn + i4;
    } else if(i4 < c1){ int o=i4-c0; v=*(const float4*)(sp.W_xproj+o);   dst=sp.wX+o; }
    else if(i4 < c2){   int o=i4-c1; v=*(const float4*)(sp.W_dt+o);      dst=sp.wDt+o; }
    else {              int o=i4-c2; v=*(const float4*)(sp.W_outproj+o); dst=sp.wOut+o; }
    v4u pk={ f2bf(v.x), f2bf(v.y), f2bf(v.z), f2bf(v.w) };
    *(v4u*)dst = pk;
    return;
  }
  if(blk < 13056){                       // ---- sg/cb prep ----
    int wid=t>>6, lane=t&63;
    int ridx = (blk-9984)*4 + wid;       // l*3072+e
    int l = ridx/3072;
    const float* wr = sp.W_inproj + (size_t)ridx*512;
    const float* gg = sp.ln_g + l*512;
    const float* bb = sp.ln_b + l*512;
    float sgv=0.f, cbv=0.f;
#pragma unroll
    for(int i=0;i<8;i++){ int k=lane*8+i; float w=wr[k]; sgv+=gg[k]*w; cbv+=bb[k]*w; }
#pragma unroll
    for(int off=1; off<64; off<<=1){ sgv+=__shfl_xor(sgv,off); cbv+=__shfl_xor(cbv,off); }
    if(lane==0){ sp.sg[ridx]=sgv; sp.cb[ridx]=cbv; }
    return;
  }
  // ---- input MLP GEMM: 64x64 tile, K=64; epilogue adds layer-0 LN stats ----
  const int mb=blk-13056, mt=mb>>3, nt=mb&7;
  const int m0=mt*64, n0=nt*64;
  const int lane=t&63, wid=t>>6;
  const int wm=wid>>1, wn=wid&1, qd=lane>>4, lr=lane&15;
  const int r=t>>2, cq=t&3;
  {
    const float4* ax=(const float4*)(sp.x + (size_t)(m0+r)*68 + 4 + cq*16);
    const float4* bx=(const float4*)(sp.w_in + (size_t)(n0+r)*64 + cq*16);
    float4 av0=ax[0], av1=ax[1], av2=ax[2], av3=ax[3];
    float4 bv0=bx[0], bv1=bx[1], bv2=bx[2], bv3=bx[3];
    v4u pa0={f2bf(av0.x),f2bf(av0.y),f2bf(av0.z),f2bf(av0.w)};
    v4u pa1={f2bf(av1.x),f2bf(av1.y),f2bf(av1.z),f2bf(av1.w)};
    v4u pa2={f2bf(av2.x),f2bf(av2.y),f2bf(av2.z),f2bf(av2.w)};
    v4u pa3={f2bf(av3.x),f2bf(av3.y),f2bf(av3.z),f2bf(av3.w)};
    v4u pb0={f2bf(bv0.x),f2bf(bv0.y),f2bf(bv0.z),f2bf(bv0.w)};
    v4u pb1={f2bf(bv1.x),f2bf(bv1.y),f2bf(bv1.z),f2bf(bv1.w)};
    v4u pb2={f2bf(bv2.x),f2bf(bv2.y),f2bf(bv2.z),f2bf(bv2.w)};
    v4u pb3={f2bf(bv3.x),f2bf(bv3.y),f2bf(bv3.z),f2bf(bv3.w)};
    u16* aw=As+r*72+cq*16; u16* bw=Bs+r*72+cq*16;
    *(v4u*)(aw)=pa0; *(v4u*)(aw+4)=pa1; *(v4u*)(aw+8)=pa2; *(v4u*)(aw+12)=pa3;
    *(v4u*)(bw)=pb0; *(v4u*)(bw+4)=pb1; *(v4u*)(bw+8)=pb2; *(v4u*)(bw+12)=pb3;
  }
  __syncthreads();
  v4f acc[2][2];
#pragma unroll
  for(int i=0;i<2;i++)
#pragma unroll
    for(int j=0;j<2;j++) acc[i][j]=v4f{0.f,0.f,0.f,0.f};
#pragma unroll
  for(int s=0;s<2;s++){
    v8s af[2], bfv[2];
#pragma unroll
    for(int i=0;i<2;i++) af[i] =*(const v8s*)(As+(wm*32+i*16+lr)*72+s*32+qd*8);
#pragma unroll
    for(int j=0;j<2;j++) bfv[j]=*(const v8s*)(Bs+(wn*32+j*16+lr)*72+s*32+qd*8);
#pragma unroll
    for(int i=0;i<2;i++)
#pragma unroll
      for(int j=0;j<2;j++)
        acc[i][j]=__builtin_amdgcn_mfma_f32_16x16x32_bf16(af[i],bfv[j],acc[i][j],0,0,0);
  }
#pragma unroll
  for(int i=0;i<2;i++)
#pragma unroll
    for(int rr=0;rr<4;rr++){
      const int gb=m0+wm*32+i*16+qd*4+rr;
      const int ge0=n0+wn*32+lr, ge1=ge0+16;
      float hv0=fmaxf(acc[i][0][rr]+sp.b_in[ge0],0.f);
      float hv1=fmaxf(acc[i][1][rr]+sp.b_in[ge1],0.f);
      sp.h[(size_t)gb*512+ge0]=hv0; sp.hb[(size_t)gb*512+ge0]=f2bf(hv0);
      sp.h[(size_t)gb*512+ge1]=hv1; sp.hb[(size_t)gb*512+ge1]=f2bf(hv1);
      float p1=hv0+hv1, p2=hv0*hv0+hv1*hv1;
      p1+=__shfl_xor(p1,1); p2+=__shfl_xor(p2,1);
      p1+=__shfl_xor(p1,2); p2+=__shfl_xor(p2,2);
      p1+=__shfl_xor(p1,4); p2+=__shfl_xor(p2,4);
      p1+=__shfl_xor(p1,8); p2+=__shfl_xor(p2,8);
      if(lr==0){ atomicAdd(sp.st0+gb*2,p1); atomicAdd(sp.st0+gb*2+1,p2); }
    }
}

// ---------------------------------------------------------------------------
// G1, algebraic fused LN, global_load_lds staging (XOR-swizzled, unpadded):
// data chunk q of row r lives at LDS slot p = q^(r&7); producer lanes write
// contiguous 16B slots (HW: base+lane*16), consumer ds_read_b128 is <=2-way.
// acc = hb @ (g*W)^T; val = rs*(acc - mu*sg) + cb; stats read from st.
// grid (48 nt, 16 mt), K=512 as 8 chunks of 64, m97 2-barrier loop.
// ---------------------------------------------------------------------------
__global__ __launch_bounds__(256) void gemm1_ln(
  const u16* __restrict__ hb, const u16* __restrict__ Wp,
  const float* __restrict__ sg, const float* __restrict__ cb,
  const float* __restrict__ st,
  const float* __restrict__ convw, const float* __restrict__ convb,
  u16* __restrict__ u, u16* __restrict__ zs)
{
  __shared__ u16 As[64*64];
  __shared__ u16 Bs[64*64];
  const int tid=threadIdx.x, lane=tid&63, wid=tid>>6;
  const int wm=wid>>1, wn=wid&1, qd=lane>>4, lr=lane&15;
  const int m0=blockIdx.y*64, n0=blockIdx.x*64;
  // producer: wave wid covers slots [wid*128, wid*128+128) via 2 insts
  const int s0=wid*128+lane, s1=s0+64;
  const int r0=s0>>3, q0=(s0&7)^(r0&7);
  const int r1=s1>>3, q1=(s1&7)^(r1&7);
  const u16* gA0 = hb + (size_t)(m0+r0)*512 + q0*8;
  const u16* gA1 = hb + (size_t)(m0+r1)*512 + q1*8;
  const u16* gB0 = Wp + (size_t)(n0+r0)*512 + q0*8;
  const u16* gB1 = Wp + (size_t)(n0+r1)*512 + q1*8;
  const int wb = __builtin_amdgcn_readfirstlane(wid);
  u16* lA0 = As + wb*1024;  u16* lA1 = As + wb*1024 + 512;
  u16* lB0 = Bs + wb*1024;  u16* lB1 = Bs + wb*1024 + 512;

  v4f acc[2][2];
#pragma unroll
  for(int i=0;i<2;i++)
#pragma unroll
    for(int j=0;j<2;j++) acc[i][j]=v4f{0.f,0.f,0.f,0.f};
  const int pxb = lr&7;

#pragma unroll
  for(int c=0;c<8;c++){
    __syncthreads();
    gl16(gA0 + c*64, lA0); gl16(gA1 + c*64, lA1);
    gl16(gB0 + c*64, lB0); gl16(gB1 + c*64, lB1);
    __syncthreads();                    // compiler drains vmcnt before barrier
#pragma unroll
    for(int s=0;s<2;s++){
      const int px=(s*4+qd)^pxb;
      v8s af[2], bfv[2];
#pragma unroll
      for(int i=0;i<2;i++) af[i] =*(const v8s*)(As+(wm*32+i*16+lr)*64+px*8);
#pragma unroll
      for(int j=0;j<2;j++) bfv[j]=*(const v8s*)(Bs+(wn*32+j*16+lr)*64+px*8);
#pragma unroll
      for(int i=0;i<2;i++)
#pragma unroll
        for(int j=0;j<2;j++)
          acc[i][j]=__builtin_amdgcn_mfma_f32_16x16x32_bf16(af[i],bfv[j],acc[i][j],0,0,0);
    }
  }

#pragma unroll
  for(int i=0;i<2;i++){
    const int gb0=m0+wm*32+i*16+qd*4;
#pragma unroll
    for(int r=0;r<4;r++){
      const int gb=gb0+r;
      float mu=st[gb*2]*(1.f/512.f);
      float rs=rsqrtf(st[gb*2+1]*(1.f/512.f)-mu*mu+1e-5f);
#pragma unroll
      for(int j=0;j<2;j++){
        const int ge=n0+wn*32+j*16+lr;
        float val = rs*(acc[i][j][r] - mu*sg[ge]) + cb[ge];
        if(ge<1536){
          u[(size_t)gb*1536+ge]=f2bf(siluf(val*convw[ge*4+3]+convb[ge]));
        }else{
          zs[(size_t)gb*1536+(ge-1536)]=f2bf(siluf(val));
        }
      }
    }
  }
}

// ---------------------------------------------------------------------------
// G2: u @ W_xproj^T, split-K=8 -> xpart[z][1024][96]. grid (8 z, 16 mt).
// (R7 verbatim)
// ---------------------------------------------------------------------------
__global__ __launch_bounds__(256) void gemm2(
  const u16* __restrict__ A, const u16* __restrict__ wX,
  float* __restrict__ xpart)
{
  __shared__ u16 As[64*40];
  __shared__ u16 Bs[96*40];
  const int tid=threadIdx.x, lane=tid&63, wid=tid>>6;
  const int wm=wid>>1, wn=wid&1, qd=lane>>4, lr=lane&15;
  const int m0=blockIdx.y*64;
  const int k0=blockIdx.x*192;
  const int r_=tid>>2, kg_=tid&3;
  const u16* Ap  = A  + (size_t)(m0+r_)*1536 + k0 + kg_*8;
  const u16* Bp0 = wX + (size_t)r_*1536      + k0 + kg_*8;
  const u16* Bp1 = wX + (size_t)(64+r_)*1536 + k0 + kg_*8;
  u16* Asw  = As + r_*40 + kg_*8;
  u16* Bsw0 = Bs + r_*40 + kg_*8;
  u16* Bsw1 = Bs + (64+r_)*40 + kg_*8;
  const bool hasB1 = tid<128;

  v4f acc[2][3];
#pragma unroll
  for(int i=0;i<2;i++)
#pragma unroll
    for(int j=0;j<3;j++) acc[i][j]=v4f{0.f,0.f,0.f,0.f};

  auto domfma=[&](){
    v8s af[2], bfv[3];
#pragma unroll
    for(int i=0;i<2;i++) af[i] =*(const v8s*)(As+(wm*32+i*16+lr)*40+qd*8);
#pragma unroll
    for(int j=0;j<3;j++) bfv[j]=*(const v8s*)(Bs+(wn*48+j*16+lr)*40+qd*8);
#pragma unroll
    for(int i=0;i<2;i++)
#pragma unroll
      for(int j=0;j<3;j++)
        acc[i][j]=__builtin_amdgcn_mfma_f32_16x16x32_bf16(af[i],bfv[j],acc[i][j],0,0,0);
  };

  v8s a0=*(const v8s*)(Ap),    b0x=*(const v8s*)(Bp0),    b0y{};
  v8s a1=*(const v8s*)(Ap+32), b1x=*(const v8s*)(Bp0+32), b1y{};
  if(hasB1){ b0y=*(const v8s*)(Bp1); b1y=*(const v8s*)(Bp1+32); }
  for(int it=0; it<6; it+=2){
    const int kk=it*32;
    __syncthreads();
    *(v8s*)Asw=a0; *(v8s*)Bsw0=b0x; if(hasB1) *(v8s*)Bsw1=b0y;
    __syncthreads();
    if(it+2<6){ a0=*(const v8s*)(Ap+kk+64); b0x=*(const v8s*)(Bp0+kk+64);
      if(hasB1) b0y=*(const v8s*)(Bp1+kk+64); }
    domfma();
    __syncthreads();
    *(v8s*)Asw=a1; *(v8s*)Bsw0=b1x; if(hasB1) *(v8s*)Bsw1=b1y;
    __syncthreads();
    if(it+2<6){ a1=*(const v8s*)(Ap+kk+96); b1x=*(const v8s*)(Bp0+kk+96);
      if(hasB1) b1y=*(const v8s*)(Bp1+kk+96); }
    domfma();
  }

  float* op = xpart + (size_t)blockIdx.x*98304;
#pragma unroll
  for(int i=0;i<2;i++)
#pragma unroll
    for(int j=0;j<3;j++){
      const int gb0=m0+wm*32+i*16+qd*4;
      const int ge =wn*48+j*16+lr;
#pragma unroll
      for(int r=0;r<4;r++)
        op[(size_t)(gb0+r)*96+ge]=acc[i][j][r];
    }
}

// ---------------------------------------------------------------------------
// G3 (+folded sdt): reduce 8 xpart slices -> s[b], dt; then
// y = u*(softplus(dt@W_dt^T+bdt)*s + Dp)*zs. grid (24,16). (R7 verbatim)
// ---------------------------------------------------------------------------
__global__ __launch_bounds__(256) void gemm3(
  const float* __restrict__ xpart, const u16* __restrict__ wDt,
  const float* __restrict__ bdt, const float* __restrict__ Dp,
  const u16* __restrict__ u, const u16* __restrict__ zs,
  u16* __restrict__ y)
{
  __shared__ u16 dts[64*40];
  __shared__ u16 Bs[64*40];
  __shared__ float sbl[64];
  const int tid=threadIdx.x, lane=tid&63, wid=tid>>6;
  const int wm=wid>>1, wn=wid&1, qd=lane>>4, lr=lane&15;
  const int m0=blockIdx.y*64, n0=blockIdx.x*64;
  const int r=tid>>2, sub=tid&3;

  v8s breg = *(const v8s*)(wDt + (size_t)(n0+r)*32 + sub*8);

  float a24[24];
#pragma unroll
  for(int i=0;i<24;i++) a24[i]=0.f;
#pragma unroll
  for(int z=0;z<8;z++){
    const float4* bz=(const float4*)(xpart + (size_t)z*98304 + (size_t)(m0+r)*96);
#pragma unroll
    for(int t=0;t<6;t++){
      float4 v=bz[sub+4*t];
      a24[4*t]+=v.x; a24[4*t+1]+=v.y; a24[4*t+2]+=v.z; a24[4*t+3]+=v.w;
    }
  }
  float s_=0.f;
#pragma unroll
  for(int m=0;m<4;m++) s_ += a24[8+m]*a24[16+m] + a24[12+m]*a24[20+m];
  s_ += __shfl_xor(s_,1); s_ += __shfl_xor(s_,2);
  if(sub==0) sbl[r]=s_;
  v4u p0={ f2bf(a24[0]), f2bf(a24[1]), f2bf(a24[2]), f2bf(a24[3]) };
  v4u p1={ f2bf(a24[4]), f2bf(a24[5]), f2bf(a24[6]), f2bf(a24[7]) };
  *(v4u*)(dts + r*40 + 4*sub)      = p0;
  *(v4u*)(dts + r*40 + 16 + 4*sub) = p1;
  *(v8s*)(Bs + r*40 + sub*8) = breg;
  __syncthreads();

  v4f acc[2][2];
#pragma unroll
  for(int i=0;i<2;i++)
#pragma unroll
    for(int j=0;j<2;j++) acc[i][j]=v4f{0.f,0.f,0.f,0.f};
  v8s af[2], bfv[2];
#pragma unroll
  for(int i=0;i<2;i++) af[i] =*(const v8s*)(dts+(wm*32+i*16+lr)*40+qd*8);
#pragma unroll
  for(int j=0;j<2;j++) bfv[j]=*(const v8s*)(Bs+(wn*32+j*16+lr)*40+qd*8);
#pragma unroll
  for(int i=0;i<2;i++)
#pragma unroll
    for(int j=0;j<2;j++)
      acc[i][j]=__builtin_amdgcn_mfma_f32_16x16x32_bf16(af[i],bfv[j],acc[i][j],0,0,0);

#pragma unroll
  for(int i=0;i<2;i++){
    const int lb0=wm*32+i*16+qd*4;
#pragma unroll
    for(int rr=0;rr<4;rr++){
      const int gb=m0+lb0+rr;
      const float sv=sbl[lb0+rr];
#pragma unroll
      for(int j=0;j<2;j++){
        const int ge=n0+wn*32+j*16+lr;
        float delta=softplusf(acc[i][j][rr]+bdt[ge]);
        float uu=bf2f(u[(size_t)gb*1536+ge]);
        float zz=bf2f(zs[(size_t)gb*1536+ge]);
        y[(size_t)gb*1536+ge]=f2bf(uu*(delta*sv+Dp[ge])*zz);
      }
    }
  }
}

// ---------------------------------------------------------------------------
// G4: y @ W_outproj^T, 32x32 tiles, grid (16,32)=512 blocks, K=1536 as 24
// chunks of 64, global_load_lds staging (same swizzle as G1).
// Epilogue: h += acc, write hb, atomicAdd next-layer LN stats.
// ---------------------------------------------------------------------------
__global__ __launch_bounds__(256) void gemm4(
  const u16* __restrict__ yv, const u16* __restrict__ wO,
  float* __restrict__ h, u16* __restrict__ hb, float* __restrict__ stn)
{
  __shared__ u16 As[32*64], Bs[32*64];
  const int tid=threadIdx.x, lane=tid&63, wid=tid>>6;
  const int wm=wid>>1, wn=wid&1, qd=lane>>4, lr=lane&15;
  const int m0=blockIdx.y*32, n0=blockIdx.x*32;
  const int s0=wid*64+lane;               // wave covers 64 slots of each buffer
  const int r0=s0>>3, q0=(s0&7)^(r0&7);
  const u16* gA = yv + (size_t)(m0+r0)*1536 + q0*8;
  const u16* gB = wO + (size_t)(n0+r0)*1536 + q0*8;
  const int wb = __builtin_amdgcn_readfirstlane(wid);
  u16* lA = As + wb*512;
  u16* lB = Bs + wb*512;

  v4f acc=v4f{0.f,0.f,0.f,0.f};
  const int pxb=lr&7;

#pragma unroll
  for(int c=0;c<24;c++){
    __syncthreads();
    gl16(gA + c*64, lA); gl16(gB + c*64, lB);
    __syncthreads();
#pragma unroll
    for(int s=0;s<2;s++){
      const int px=(s*4+qd)^pxb;
      v8s af=*(const v8s*)(As+(wm*16+lr)*64+px*8);
      v8s bf=*(const v8s*)(Bs+(wn*16+lr)*64+px*8);
      acc=__builtin_amdgcn_mfma_f32_16x16x32_bf16(af,bf,acc,0,0,0);
    }
  }

#pragma unroll
  for(int r=0;r<4;r++){
    const int gb=m0+wm*16+qd*4+r;
    const int ge=n0+wn*16+lr;
    const size_t idx=(size_t)gb*512+ge;
    float hv=h[idx]+acc[r];
    h[idx]=hv; hb[idx]=f2bf(hv);
    float p1=hv, p2=hv*hv;
    p1+=__shfl_xor(p1,1); p2+=__shfl_xor(p2,1);
    p1+=__shfl_xor(p1,2); p2+=__shfl_xor(p2,2);
    p1+=__shfl_xor(p1,4); p2+=__shfl_xor(p2,4);
    p1+=__shfl_xor(p1,8); p2+=__shfl_xor(p2,8);
    if(lr==0){ atomicAdd(stn+gb*2,p1); atomicAdd(stn+gb*2+1,p2); }
  }
}

// ---------------------------------------------------------------------------
// Head: lg/gate/MLP/sigmoid. One block per row. (R7 verbatim)
// ---------------------------------------------------------------------------
__global__ __launch_bounds__(256) void head_kernel(
  const float* __restrict__ x, const float* __restrict__ h,
  const float* __restrict__ wlog, const float* __restrict__ blog,
  const float* __restrict__ wg, const float* __restrict__ bg,
  const float* __restrict__ wh1, const float* __restrict__ bh1,
  const float* __restrict__ wh2, const float* __restrict__ bh2,
  float* __restrict__ out)
{
  int b = blockIdx.x, t = threadIdx.x;
  __shared__ float fused[512];
  __shared__ float part[256];
  __shared__ float z1s[32];
  float lgin = x[b*68+0]*wlog[0] + x[b*68+1]*wlog[1]
             + x[b*68+2]*wlog[2] + x[b*68+3]*wlog[3] + blog[0];
  float lg = 1.f/(1.f+__expf(-lgin));
  for(int d=t; d<512; d+=256)
    fused[d] = h[(size_t)b*512+d]*(lg*wg[d] + bg[d]);
  __syncthreads();
  int j = t&31, c = t>>5;
  float p = 0.f;
#pragma unroll
  for(int i=0;i<64;i++){ int d = c*64+i; p += fused[d]*wh1[j*512+d]; }
  part[t] = p;
  __syncthreads();
  if(t < 32){
    float z = bh1[t];
#pragma unroll
    for(int cc=0; cc<8; cc++) z += part[cc*32+t];
    z1s[t] = fmaxf(z, 0.f);
  }
  __syncthreads();
  if(t==0){
    float lo = bh2[0];
#pragma unroll
    for(int jj=0;jj<32;jj++) lo += z1s[jj]*wh2[jj];
    out[b] = 1.f/(1.f+__expf(-lo));
  }
}

// ---------------------------------------------------------------------------
extern "C" void kernel_launch(void* const* d_in, const int* in_sizes, int n_in,
                              void* d_out, int out_size, void* d_ws, size_t ws_size,
                              hipStream_t stream)
{
  const float* x        = (const float*)d_in[0];
  const float* w_in     = (const float*)d_in[1];
  const float* b_in     = (const float*)d_in[2];
  const float* ln_g     = (const float*)d_in[3];
  const float* ln_b     = (const float*)d_in[4];
  const float* W_inproj = (const float*)d_in[5];
  const float* conv_w   = (const float*)d_in[6];
  const float* conv_b   = (const float*)d_in[7];
  const float* W_xproj  = (const float*)d_in[8];
  const float* W_dt     = (const float*)d_in[9];
  const float* b_dt     = (const float*)d_in[10];
  // d_in[11] A_log: dead — scan is a single step from h0=0
  const float* D_skip   = (const float*)d_in[12];
  const float* W_outproj= (const float*)d_in[13];
  const float* w_log    = (const float*)d_in[14];
  const float* b_log    = (const float*)d_in[15];
  const float* W_gate   = (const float*)d_in[16];
  const float* b_gate   = (const float*)d_in[17];
  const float* W_h1     = (const float*)d_in[18];
  const float* b_h1     = (const float*)d_in[19];
  const float* W_h2     = (const float*)d_in[20];
  const float* b_h2     = (const float*)d_in[21];
  float* out = (float*)d_out;
  (void)in_sizes; (void)n_in; (void)out_size; (void)ws_size;

  char* ws = (char*)d_ws;
  size_t off = 0;
  auto alloc = [&](size_t bytes)->char*{
    char* p = ws + off; off = (off + bytes + 255) & ~(size_t)255; return p; };
  u16*   wIn  = (u16*)  alloc(6291456u*2);   // W' = g*W_inproj, bf16
  u16*   wX   = (u16*)  alloc(589824u*2);
  u16*   wDt  = (u16*)  alloc(196608u*2);
  u16*   wOut = (u16*)  alloc(3145728u*2);
  float* sg   = (float*)alloc(12288u*4);
  float* cb   = (float*)alloc(12288u*4);
  float* stats= (float*)alloc(10240u*4);     // [5][1024][2] LN row sums
  float* h    = (float*)alloc(524288u*4);
  u16*   hb   = (u16*)  alloc(524288u*2);
  u16*   u    = (u16*)  alloc(1572864u*2);
  u16*   zs   = (u16*)  alloc(1572864u*2);
  u16*   y    = (u16*)  alloc(1572864u*2);
  float* xpart= (float*)alloc(8u*98304u*4);  // G2 split-K partials

  hipMemsetAsync(stats, 0, 10240u*4, stream);

  SetupP sp;
  sp.x=x; sp.w_in=w_in; sp.b_in=b_in; sp.ln_g=ln_g; sp.ln_b=ln_b;
  sp.W_inproj=W_inproj; sp.W_xproj=W_xproj; sp.W_dt=W_dt; sp.W_outproj=W_outproj;
  sp.wIn=wIn; sp.wX=wX; sp.wDt=wDt; sp.wOut=wOut;
  sp.sg=sg; sp.cb=cb; sp.h=h; sp.st0=stats; sp.hb=hb;

  setup_kernel<<<13184,256,0,stream>>>(sp);

  for(int l=0;l<4;l++){
    gemm1_ln<<<dim3(48,16),256,0,stream>>>(
      hb, wIn+(size_t)l*1572864, sg+l*3072, cb+l*3072, stats+l*2048,
      conv_w+l*6144, conv_b+l*1536, u, zs);
    gemm2<<<dim3(8,16),256,0,stream>>>(
      u, wX+(size_t)l*147456, xpart);
    gemm3<<<dim3(24,16),256,0,stream>>>(
      xpart, wDt+(size_t)l*49152, b_dt+l*1536, D_skip+l*1536, u, zs, y);
    gemm4<<<dim3(16,32),256,0,stream>>>(
      y, wOut+(size_t)l*786432, h, hb, stats+(l+1)*2048);
  }

  head_kernel<<<1024,256,0,stream>>>(x, h, w_log, b_log, W_gate, b_gate,
                                     W_h1, b_h1, W_h2, b_h2, out);
}

// Round 10
// 286.175 us; speedup vs baseline: 1.1516x; 1.1516x over previous
//
#include <hip/hip_runtime.h>

typedef unsigned short u16;
typedef short v8s __attribute__((ext_vector_type(8)));
typedef float v4f __attribute__((ext_vector_type(4)));
typedef u16  v4u __attribute__((ext_vector_type(4)));

__device__ __forceinline__ float bf2f(u16 h){ return __uint_as_float(((unsigned)h)<<16); }
__device__ __forceinline__ u16 f2bf(float f){
  unsigned u = __float_as_uint(f);
  u += 0x7FFFu + ((u>>16)&1u);
  return (u16)(u>>16);
}
__device__ __forceinline__ float siluf(float x){ return x/(1.f+__expf(-x)); }
__device__ __forceinline__ float softplusf(float x){
  return (x>15.f) ? x : __logf(1.f+__expf(x));
}

// ---------------------------------------------------------------------------
// Setup mega-kernel (2 jobs by block range):
//  [0,9984)      f32->bf16 weight cvt; ln_g folded into W_inproj (W'=g*W).
//                Blocks covering W_inproj (<6144) additionally fold the
//                sg/cb row-sums: each such block spans EXACTLY 2 rows
//                (1024 elems), so sg[e]=sum g*W, cb[e]=sum beta*W come from
//                the already-loaded values via shfl+LDS reduce — this removes
//                R7's separate 3072-block job and its 25 MB re-read.
//  [9984,10112)  input MLP as MFMA GEMM (coalesced staging)
// ---------------------------------------------------------------------------
struct SetupP {
  const float *x,*w_in,*b_in,*ln_g,*ln_b,*W_inproj,*W_xproj,*W_dt,*W_outproj;
  u16 *wIn,*wX,*wDt,*wOut;
  float *sg,*cb,*h;
  u16 *hb;
};

__global__ __launch_bounds__(256) void setup_kernel(SetupP sp)
{
  __shared__ u16 As[64*72], Bs[64*72];
  __shared__ float wred[4][2];
  const int blk = blockIdx.x, t = threadIdx.x;
  if(blk < 9984){                        // ---- cvt ----
    const int c0=6291456, c1=c0+589824, c2=c1+196608;
    int i4 = (blk*256 + t)*4;
    float4 v; u16* dst;
    if(i4 < c0){                         // W_inproj: cvt + sg/cb fold
      v = *(const float4*)(sp.W_inproj + i4);
      int k = i4 & 511, ridx = i4 >> 9, l = ridx/3072;
      const float* gg = sp.ln_g + l*512 + k;
      const float* bb = sp.ln_b + l*512 + k;
      float cbp = v.x*bb[0]+v.y*bb[1]+v.z*bb[2]+v.w*bb[3];
      v.x*=gg[0]; v.y*=gg[1]; v.z*=gg[2]; v.w*=gg[3];
      float sgp = v.x+v.y+v.z+v.w;       // sum of g*W
      dst = sp.wIn + i4;
      v4u pk={ f2bf(v.x), f2bf(v.y), f2bf(v.z), f2bf(v.w) };
      *(v4u*)dst = pk;
#pragma unroll
      for(int off=1; off<64; off<<=1){ sgp+=__shfl_xor(sgp,off); cbp+=__shfl_xor(cbp,off); }
      int wv=t>>6;
      if((t&63)==0){ wred[wv][0]=sgp; wred[wv][1]=cbp; }
      __syncthreads();
      if(t==0){ sp.sg[blk*2]  =wred[0][0]+wred[1][0]; sp.cb[blk*2]  =wred[0][1]+wred[1][1]; }
      if(t==128){ sp.sg[blk*2+1]=wred[2][0]+wred[3][0]; sp.cb[blk*2+1]=wred[2][1]+wred[3][1]; }
      return;
    }
    if(i4 < c1){ int o=i4-c0; v=*(const float4*)(sp.W_xproj+o);   dst=sp.wX+o; }
    else if(i4 < c2){ int o=i4-c1; v=*(const float4*)(sp.W_dt+o); dst=sp.wDt+o; }
    else { int o=i4-c2; v=*(const float4*)(sp.W_outproj+o); dst=sp.wOut+o; }
    v4u pk={ f2bf(v.x), f2bf(v.y), f2bf(v.z), f2bf(v.w) };
    *(v4u*)dst = pk;
    return;
  }
  // ---- input MLP GEMM: 64x64 tile, K=64 ----
  const int mb=blk-9984, mt=mb>>3, nt=mb&7;
  const int m0=mt*64, n0=nt*64;
  const int lane=t&63, wid=t>>6;
  const int wm=wid>>1, wn=wid&1, qd=lane>>4, lr=lane&15;
  const int r=t>>2, cq=t&3;
  {
    const float4* ax=(const float4*)(sp.x + (size_t)(m0+r)*68 + 4 + cq*16);
    const float4* bx=(const float4*)(sp.w_in + (size_t)(n0+r)*64 + cq*16);
    float4 av0=ax[0], av1=ax[1], av2=ax[2], av3=ax[3];
    float4 bv0=bx[0], bv1=bx[1], bv2=bx[2], bv3=bx[3];
    v4u pa0={f2bf(av0.x),f2bf(av0.y),f2bf(av0.z),f2bf(av0.w)};
    v4u pa1={f2bf(av1.x),f2bf(av1.y),f2bf(av1.z),f2bf(av1.w)};
    v4u pa2={f2bf(av2.x),f2bf(av2.y),f2bf(av2.z),f2bf(av2.w)};
    v4u pa3={f2bf(av3.x),f2bf(av3.y),f2bf(av3.z),f2bf(av3.w)};
    v4u pb0={f2bf(bv0.x),f2bf(bv0.y),f2bf(bv0.z),f2bf(bv0.w)};
    v4u pb1={f2bf(bv1.x),f2bf(bv1.y),f2bf(bv1.z),f2bf(bv1.w)};
    v4u pb2={f2bf(bv2.x),f2bf(bv2.y),f2bf(bv2.z),f2bf(bv2.w)};
    v4u pb3={f2bf(bv3.x),f2bf(bv3.y),f2bf(bv3.z),f2bf(bv3.w)};
    u16* aw=As+r*72+cq*16; u16* bw=Bs+r*72+cq*16;
    *(v4u*)(aw)=pa0; *(v4u*)(aw+4)=pa1; *(v4u*)(aw+8)=pa2; *(v4u*)(aw+12)=pa3;
    *(v4u*)(bw)=pb0; *(v4u*)(bw+4)=pb1; *(v4u*)(bw+8)=pb2; *(v4u*)(bw+12)=pb3;
  }
  __syncthreads();
  v4f acc[2][2];
#pragma unroll
  for(int i=0;i<2;i++)
#pragma unroll
    for(int j=0;j<2;j++) acc[i][j]=v4f{0.f,0.f,0.f,0.f};
#pragma unroll
  for(int s=0;s<2;s++){
    v8s af[2], bfv[2];
#pragma unroll
    for(int i=0;i<2;i++) af[i] =*(const v8s*)(As+(wm*32+i*16+lr)*72+s*32+qd*8);
#pragma unroll
    for(int j=0;j<2;j++) bfv[j]=*(const v8s*)(Bs+(wn*32+j*16+lr)*72+s*32+qd*8);
#pragma unroll
    for(int i=0;i<2;i++)
#pragma unroll
      for(int j=0;j<2;j++)
        acc[i][j]=__builtin_amdgcn_mfma_f32_16x16x32_bf16(af[i],bfv[j],acc[i][j],0,0,0);
  }
#pragma unroll
  for(int i=0;i<2;i++)
#pragma unroll
    for(int j=0;j<2;j++){
      const int gb0=m0+wm*32+i*16+qd*4;
      const int ge =n0+wn*32+j*16+lr;
#pragma unroll
      for(int rr=0;rr<4;rr++){
        float hv=fmaxf(acc[i][j][rr]+sp.b_in[ge],0.f);
        const size_t idx=(size_t)(gb0+rr)*512+ge;
        sp.h[idx]=hv; sp.hb[idx]=f2bf(hv);
      }
    }
}

// ---------------------------------------------------------------------------
// G1, algebraic fused LN with in-staging stats (R7 verbatim — best measured):
// acc = hb @ (g*W)^T; S1,S2 accumulated from the staged registers;
// val = rs*(acc - mu*sg) + cb. grid (48,16), BK=64 chunks, depth-2 prefetch.
// ---------------------------------------------------------------------------
__global__ __launch_bounds__(256) void gemm1_ln(
  const u16* __restrict__ hb, const u16* __restrict__ Wp,
  const float* __restrict__ sg, const float* __restrict__ cb,
  const float* __restrict__ convw, const float* __restrict__ convb,
  u16* __restrict__ u, u16* __restrict__ zs)
{
  __shared__ u16 As[64*72], Bs[64*72];
  __shared__ float sS1[64], sS2[64];
  const int tid=threadIdx.x, lane=tid&63, wid=tid>>6;
  const int wm=wid>>1, wn=wid&1, qd=lane>>4, lr=lane&15;
  const int m0=blockIdx.y*64, n0=blockIdx.x*64;
  const int r_=tid>>2, cq=tid&3;
  const u16* Ap = hb + (size_t)(m0+r_)*512 + cq*16;
  const u16* Bp = Wp + (size_t)(n0+r_)*512 + cq*16;
  u16* Asw = As + r_*72 + cq*16;
  u16* Bsw = Bs + r_*72 + cq*16;

  v4f acc[2][2];
#pragma unroll
  for(int i=0;i<2;i++)
#pragma unroll
    for(int j=0;j<2;j++) acc[i][j]=v4f{0.f,0.f,0.f,0.f};
  float s1=0.f, s2=0.f;

  auto statAcc=[&](v8s v){
#pragma unroll
    for(int e=0;e<8;e++){ float f=bf2f((u16)v[e]); s1+=f; s2+=f*f; }
  };
  auto domfma=[&](){
#pragma unroll
    for(int s=0;s<2;s++){
      v8s af[2], bfv[2];
#pragma unroll
      for(int i=0;i<2;i++) af[i] =*(const v8s*)(As+(wm*32+i*16+lr)*72+s*32+qd*8);
#pragma unroll
      for(int j=0;j<2;j++) bfv[j]=*(const v8s*)(Bs+(wn*32+j*16+lr)*72+s*32+qd*8);
#pragma unroll
      for(int i=0;i<2;i++)
#pragma unroll
        for(int j=0;j<2;j++)
          acc[i][j]=__builtin_amdgcn_mfma_f32_16x16x32_bf16(af[i],bfv[j],acc[i][j],0,0,0);
    }
  };

  v8s a0a=*(const v8s*)(Ap),    a0b=*(const v8s*)(Ap+8);
  v8s b0a=*(const v8s*)(Bp),    b0b=*(const v8s*)(Bp+8);
  v8s a1a=*(const v8s*)(Ap+64), a1b=*(const v8s*)(Ap+72);
  v8s b1a=*(const v8s*)(Bp+64), b1b=*(const v8s*)(Bp+72);
  for(int c=0;c<8;c+=2){
    __syncthreads();
    *(v8s*)Asw=a0a; *(v8s*)(Asw+8)=a0b;
    *(v8s*)Bsw=b0a; *(v8s*)(Bsw+8)=b0b;
    statAcc(a0a); statAcc(a0b);
    __syncthreads();
    if(c+2<8){
      a0a=*(const v8s*)(Ap+(c+2)*64); a0b=*(const v8s*)(Ap+(c+2)*64+8);
      b0a=*(const v8s*)(Bp+(c+2)*64); b0b=*(const v8s*)(Bp+(c+2)*64+8);
    }
    domfma();
    __syncthreads();
    *(v8s*)Asw=a1a; *(v8s*)(Asw+8)=a1b;
    *(v8s*)Bsw=b1a; *(v8s*)(Bsw+8)=b1b;
    statAcc(a1a); statAcc(a1b);
    __syncthreads();
    if(c+3<8){
      a1a=*(const v8s*)(Ap+(c+3)*64); a1b=*(const v8s*)(Ap+(c+3)*64+8);
      b1a=*(const v8s*)(Bp+(c+3)*64); b1b=*(const v8s*)(Bp+(c+3)*64+8);
    }
    domfma();
  }

  // stats: 4 threads (cq=0..3, adjacent lanes) cover a row's 512 cols
  s1+=__shfl_xor(s1,1); s2+=__shfl_xor(s2,1);
  s1+=__shfl_xor(s1,2); s2+=__shfl_xor(s2,2);
  if(cq==0){ sS1[r_]=s1; sS2[r_]=s2; }
  __syncthreads();

#pragma unroll
  for(int i=0;i<2;i++){
    const int lb0=wm*32+i*16+qd*4;
#pragma unroll
    for(int r=0;r<4;r++){
      const int lb=lb0+r, gb=m0+lb;
      float mu=sS1[lb]*(1.f/512.f);
      float rs=rsqrtf(sS2[lb]*(1.f/512.f)-mu*mu+1e-5f);
#pragma unroll
      for(int j=0;j<2;j++){
        const int ge=n0+wn*32+j*16+lr;
        float val = rs*(acc[i][j][r] - mu*sg[ge]) + cb[ge];
        if(ge<1536){
          u[(size_t)gb*1536+ge]=f2bf(siluf(val*convw[ge*4+3]+convb[ge]));
        }else{
          zs[(size_t)gb*1536+(ge-1536)]=f2bf(siluf(val));
        }
      }
    }
  }
}

// ---------------------------------------------------------------------------
// G2: u @ W_xproj^T, split-K=8 -> xpart[z][1024][96]. grid (8 z, 16 mt).
// (R7 verbatim)
// ---------------------------------------------------------------------------
__global__ __launch_bounds__(256) void gemm2(
  const u16* __restrict__ A, const u16* __restrict__ wX,
  float* __restrict__ xpart)
{
  __shared__ u16 As[64*40];
  __shared__ u16 Bs[96*40];
  const int tid=threadIdx.x, lane=tid&63, wid=tid>>6;
  const int wm=wid>>1, wn=wid&1, qd=lane>>4, lr=lane&15;
  const int m0=blockIdx.y*64;
  const int k0=blockIdx.x*192;
  const int r_=tid>>2, kg_=tid&3;
  const u16* Ap  = A  + (size_t)(m0+r_)*1536 + k0 + kg_*8;
  const u16* Bp0 = wX + (size_t)r_*1536      + k0 + kg_*8;
  const u16* Bp1 = wX + (size_t)(64+r_)*1536 + k0 + kg_*8;
  u16* Asw  = As + r_*40 + kg_*8;
  u16* Bsw0 = Bs + r_*40 + kg_*8;
  u16* Bsw1 = Bs + (64+r_)*40 + kg_*8;
  const bool hasB1 = tid<128;

  v4f acc[2][3];
#pragma unroll
  for(int i=0;i<2;i++)
#pragma unroll
    for(int j=0;j<3;j++) acc[i][j]=v4f{0.f,0.f,0.f,0.f};

  auto domfma=[&](){
    v8s af[2], bfv[3];
#pragma unroll
    for(int i=0;i<2;i++) af[i] =*(const v8s*)(As+(wm*32+i*16+lr)*40+qd*8);
#pragma unroll
    for(int j=0;j<3;j++) bfv[j]=*(const v8s*)(Bs+(wn*48+j*16+lr)*40+qd*8);
#pragma unroll
    for(int i=0;i<2;i++)
#pragma unroll
      for(int j=0;j<3;j++)
        acc[i][j]=__builtin_amdgcn_mfma_f32_16x16x32_bf16(af[i],bfv[j],acc[i][j],0,0,0);
  };

  v8s a0=*(const v8s*)(Ap),    b0x=*(const v8s*)(Bp0),    b0y{};
  v8s a1=*(const v8s*)(Ap+32), b1x=*(const v8s*)(Bp0+32), b1y{};
  if(hasB1){ b0y=*(const v8s*)(Bp1); b1y=*(const v8s*)(Bp1+32); }
  for(int it=0; it<6; it+=2){
    const int kk=it*32;
    __syncthreads();
    *(v8s*)Asw=a0; *(v8s*)Bsw0=b0x; if(hasB1) *(v8s*)Bsw1=b0y;
    __syncthreads();
    if(it+2<6){ a0=*(const v8s*)(Ap+kk+64); b0x=*(const v8s*)(Bp0+kk+64);
      if(hasB1) b0y=*(const v8s*)(Bp1+kk+64); }
    domfma();
    __syncthreads();
    *(v8s*)Asw=a1; *(v8s*)Bsw0=b1x; if(hasB1) *(v8s*)Bsw1=b1y;
    __syncthreads();
    if(it+2<6){ a1=*(const v8s*)(Ap+kk+96); b1x=*(const v8s*)(Bp0+kk+96);
      if(hasB1) b1y=*(const v8s*)(Bp1+kk+96); }
    domfma();
  }

  float* op = xpart + (size_t)blockIdx.x*98304;
#pragma unroll
  for(int i=0;i<2;i++)
#pragma unroll
    for(int j=0;j<3;j++){
      const int gb0=m0+wm*32+i*16+qd*4;
      const int ge =wn*48+j*16+lr;
#pragma unroll
      for(int r=0;r<4;r++)
        op[(size_t)(gb0+r)*96+ge]=acc[i][j][r];
    }
}

// ---------------------------------------------------------------------------
// G3 (+folded sdt): reduce 8 xpart slices -> s[b], dt; then
// y = u*(softplus(dt@W_dt^T+bdt)*s + Dp)*zs. grid (24,16). (R7 verbatim)
// ---------------------------------------------------------------------------
__global__ __launch_bounds__(256) void gemm3(
  const float* __restrict__ xpart, const u16* __restrict__ wDt,
  const float* __restrict__ bdt, const float* __restrict__ Dp,
  const u16* __restrict__ u, const u16* __restrict__ zs,
  u16* __restrict__ y)
{
  __shared__ u16 dts[64*40];
  __shared__ u16 Bs[64*40];
  __shared__ float sbl[64];
  const int tid=threadIdx.x, lane=tid&63, wid=tid>>6;
  const int wm=wid>>1, wn=wid&1, qd=lane>>4, lr=lane&15;
  const int m0=blockIdx.y*64, n0=blockIdx.x*64;
  const int r=tid>>2, sub=tid&3;

  v8s breg = *(const v8s*)(wDt + (size_t)(n0+r)*32 + sub*8);

  float a24[24];
#pragma unroll
  for(int i=0;i<24;i++) a24[i]=0.f;
#pragma unroll
  for(int z=0;z<8;z++){
    const float4* bz=(const float4*)(xpart + (size_t)z*98304 + (size_t)(m0+r)*96);
#pragma unroll
    for(int t=0;t<6;t++){
      float4 v=bz[sub+4*t];
      a24[4*t]+=v.x; a24[4*t+1]+=v.y; a24[4*t+2]+=v.z; a24[4*t+3]+=v.w;
    }
  }
  float s_=0.f;
#pragma unroll
  for(int m=0;m<4;m++) s_ += a24[8+m]*a24[16+m] + a24[12+m]*a24[20+m];
  s_ += __shfl_xor(s_,1); s_ += __shfl_xor(s_,2);
  if(sub==0) sbl[r]=s_;
  v4u p0={ f2bf(a24[0]), f2bf(a24[1]), f2bf(a24[2]), f2bf(a24[3]) };
  v4u p1={ f2bf(a24[4]), f2bf(a24[5]), f2bf(a24[6]), f2bf(a24[7]) };
  *(v4u*)(dts + r*40 + 4*sub)      = p0;
  *(v4u*)(dts + r*40 + 16 + 4*sub) = p1;
  *(v8s*)(Bs + r*40 + sub*8) = breg;
  __syncthreads();

  v4f acc[2][2];
#pragma unroll
  for(int i=0;i<2;i++)
#pragma unroll
    for(int j=0;j<2;j++) acc[i][j]=v4f{0.f,0.f,0.f,0.f};
  v8s af[2], bfv[2];
#pragma unroll
  for(int i=0;i<2;i++) af[i] =*(const v8s*)(dts+(wm*32+i*16+lr)*40+qd*8);
#pragma unroll
  for(int j=0;j<2;j++) bfv[j]=*(const v8s*)(Bs+(wn*32+j*16+lr)*40+qd*8);
#pragma unroll
  for(int i=0;i<2;i++)
#pragma unroll
    for(int j=0;j<2;j++)
      acc[i][j]=__builtin_amdgcn_mfma_f32_16x16x32_bf16(af[i],bfv[j],acc[i][j],0,0,0);

#pragma unroll
  for(int i=0;i<2;i++){
    const int lb0=wm*32+i*16+qd*4;
#pragma unroll
    for(int rr=0;rr<4;rr++){
      const int gb=m0+lb0+rr;
      const float sv=sbl[lb0+rr];
#pragma unroll
      for(int j=0;j<2;j++){
        const int ge=n0+wn*32+j*16+lr;
        float delta=softplusf(acc[i][j][rr]+bdt[ge]);
        float uu=bf2f(u[(size_t)gb*1536+ge]);
        float zz=bf2f(zs[(size_t)gb*1536+ge]);
        y[(size_t)gb*1536+ge]=f2bf(uu*(delta*sv+Dp[ge])*zz);
      }
    }
  }
}

// ---------------------------------------------------------------------------
// G4: y @ W_outproj^T, 32x32 tiles, grid (16,32)=512 blocks, full K=1536
// as 24 BK=64 chunks, depth-2 prefetch. Epilogue: h += acc, write hb.
// (R7 verbatim)
// ---------------------------------------------------------------------------
__global__ __launch_bounds__(256) void gemm4(
  const u16* __restrict__ yv, const u16* __restrict__ wO,
  float* __restrict__ h, u16* __restrict__ hb)
{
  __shared__ u16 As[32*72], Bs[32*72];
  const int tid=threadIdx.x, lane=tid&63, wid=tid>>6;
  const int wm=wid>>1, wn=wid&1, qd=lane>>4, lr=lane&15;
  const int m0=blockIdx.y*32, n0=blockIdx.x*32;
  const int half=tid>>7, ts=tid&127;
  const int r_=ts>>2, cq=ts&3;
  const u16* Gp = (half ? wO + (size_t)(n0+r_)*1536
                        : yv + (size_t)(m0+r_)*1536) + cq*16;
  u16* Sw = (half ? Bs : As) + r_*72 + cq*16;

  v4f acc=v4f{0.f,0.f,0.f,0.f};
  auto domfma=[&](){
#pragma unroll
    for(int s=0;s<2;s++){
      v8s af=*(const v8s*)(As+(wm*16+lr)*72+s*32+qd*8);
      v8s bf=*(const v8s*)(Bs+(wn*16+lr)*72+s*32+qd*8);
      acc=__builtin_amdgcn_mfma_f32_16x16x32_bf16(af,bf,acc,0,0,0);
    }
  };

  v8s g0a=*(const v8s*)(Gp),    g0b=*(const v8s*)(Gp+8);
  v8s g1a=*(const v8s*)(Gp+64), g1b=*(const v8s*)(Gp+72);
  for(int c=0;c<24;c+=2){
    __syncthreads();
    *(v8s*)Sw=g0a; *(v8s*)(Sw+8)=g0b;
    __syncthreads();
    if(c+2<24){ g0a=*(const v8s*)(Gp+(c+2)*64); g0b=*(const v8s*)(Gp+(c+2)*64+8); }
    domfma();
    __syncthreads();
    *(v8s*)Sw=g1a; *(v8s*)(Sw+8)=g1b;
    __syncthreads();
    if(c+3<24){ g1a=*(const v8s*)(Gp+(c+3)*64); g1b=*(const v8s*)(Gp+(c+3)*64+8); }
    domfma();
  }

#pragma unroll
  for(int r=0;r<4;r++){
    const int gb=m0+wm*16+qd*4+r;
    const int ge=n0+wn*16+lr;
    const size_t idx=(size_t)gb*512+ge;
    float hv=h[idx]+acc[r];
    h[idx]=hv; hb[idx]=f2bf(hv);
  }
}

// ---------------------------------------------------------------------------
// Head: lg/gate/MLP/sigmoid. One block per row. (R7 verbatim)
// ---------------------------------------------------------------------------
__global__ __launch_bounds__(256) void head_kernel(
  const float* __restrict__ x, const float* __restrict__ h,
  const float* __restrict__ wlog, const float* __restrict__ blog,
  const float* __restrict__ wg, const float* __restrict__ bg,
  const float* __restrict__ wh1, const float* __restrict__ bh1,
  const float* __restrict__ wh2, const float* __restrict__ bh2,
  float* __restrict__ out)
{
  int b = blockIdx.x, t = threadIdx.x;
  __shared__ float fused[512];
  __shared__ float part[256];
  __shared__ float z1s[32];
  float lgin = x[b*68+0]*wlog[0] + x[b*68+1]*wlog[1]
             + x[b*68+2]*wlog[2] + x[b*68+3]*wlog[3] + blog[0];
  float lg = 1.f/(1.f+__expf(-lgin));
  for(int d=t; d<512; d+=256)
    fused[d] = h[(size_t)b*512+d]*(lg*wg[d] + bg[d]);
  __syncthreads();
  int j = t&31, c = t>>5;
  float p = 0.f;
#pragma unroll
  for(int i=0;i<64;i++){ int d = c*64+i; p += fused[d]*wh1[j*512+d]; }
  part[t] = p;
  __syncthreads();
  if(t < 32){
    float z = bh1[t];
#pragma unroll
    for(int cc=0; cc<8; cc++) z += part[cc*32+t];
    z1s[t] = fmaxf(z, 0.f);
  }
  __syncthreads();
  if(t==0){
    float lo = bh2[0];
#pragma unroll
    for(int jj=0;jj<32;jj++) lo += z1s[jj]*wh2[jj];
    out[b] = 1.f/(1.f+__expf(-lo));
  }
}

// ---------------------------------------------------------------------------
extern "C" void kernel_launch(void* const* d_in, const int* in_sizes, int n_in,
                              void* d_out, int out_size, void* d_ws, size_t ws_size,
                              hipStream_t stream)
{
  const float* x        = (const float*)d_in[0];
  const float* w_in     = (const float*)d_in[1];
  const float* b_in     = (const float*)d_in[2];
  const float* ln_g     = (const float*)d_in[3];
  const float* ln_b     = (const float*)d_in[4];
  const float* W_inproj = (const float*)d_in[5];
  const float* conv_w   = (const float*)d_in[6];
  const float* conv_b   = (const float*)d_in[7];
  const float* W_xproj  = (const float*)d_in[8];
  const float* W_dt     = (const float*)d_in[9];
  const float* b_dt     = (const float*)d_in[10];
  // d_in[11] A_log: dead — scan is a single step from h0=0
  const float* D_skip   = (const float*)d_in[12];
  const float* W_outproj= (const float*)d_in[13];
  const float* w_log    = (const float*)d_in[14];
  const float* b_log    = (const float*)d_in[15];
  const float* W_gate   = (const float*)d_in[16];
  const float* b_gate   = (const float*)d_in[17];
  const float* W_h1     = (const float*)d_in[18];
  const float* b_h1     = (const float*)d_in[19];
  const float* W_h2     = (const float*)d_in[20];
  const float* b_h2     = (const float*)d_in[21];
  float* out = (float*)d_out;
  (void)in_sizes; (void)n_in; (void)out_size; (void)ws_size;

  char* ws = (char*)d_ws;
  size_t off = 0;
  auto alloc = [&](size_t bytes)->char*{
    char* p = ws + off; off = (off + bytes + 255) & ~(size_t)255; return p; };
  u16*   wIn  = (u16*)  alloc(6291456u*2);   // W' = g*W_inproj, bf16
  u16*   wX   = (u16*)  alloc(589824u*2);
  u16*   wDt  = (u16*)  alloc(196608u*2);
  u16*   wOut = (u16*)  alloc(3145728u*2);
  float* sg   = (float*)alloc(12288u*4);
  float* cb   = (float*)alloc(12288u*4);
  float* h    = (float*)alloc(524288u*4);
  u16*   hb   = (u16*)  alloc(524288u*2);
  u16*   u    = (u16*)  alloc(1572864u*2);
  u16*   zs   = (u16*)  alloc(1572864u*2);
  u16*   y    = (u16*)  alloc(1572864u*2);
  float* xpart= (float*)alloc(8u*98304u*4);  // G2 split-K partials

  SetupP sp;
  sp.x=x; sp.w_in=w_in; sp.b_in=b_in; sp.ln_g=ln_g; sp.ln_b=ln_b;
  sp.W_inproj=W_inproj; sp.W_xproj=W_xproj; sp.W_dt=W_dt; sp.W_outproj=W_outproj;
  sp.wIn=wIn; sp.wX=wX; sp.wDt=wDt; sp.wOut=wOut;
  sp.sg=sg; sp.cb=cb; sp.h=h; sp.hb=hb;

  setup_kernel<<<10112,256,0,stream>>>(sp);

  for(int l=0;l<4;l++){
    gemm1_ln<<<dim3(48,16),256,0,stream>>>(
      hb, wIn+(size_t)l*1572864, sg+l*3072, cb+l*3072,
      conv_w+l*6144, conv_b+l*1536, u, zs);
    gemm2<<<dim3(8,16),256,0,stream>>>(
      u, wX+(size_t)l*147456, xpart);
    gemm3<<<dim3(24,16),256,0,stream>>>(
      xpart, wDt+(size_t)l*49152, b_dt+l*1536, D_skip+l*1536, u, zs, y);
    gemm4<<<dim3(16,32),256,0,stream>>>(
      y, wOut+(size_t)l*786432, h, hb);
  }

  head_kernel<<<1024,256,0,stream>>>(x, h, w_log, b_log, W_gate, b_gate,
                                     W_h1, b_h1, W_h2, b_h2, out);
}